// Round 10
// baseline (191.130 us; speedup 1.0000x reference)
//
#include <hip/hip_runtime.h>

// SFM recurrent model via MFMA: B=2048, T=60, D=6, H=64, F=10, O=1.
//
// R1-R3: VALU readlane-GEMV, 183 us. R4: MFMA split-bf16 -> 100 us.
// R5: pre-split bf16 in LDS -> 83 us. R6: 2 blk/CU slide -> (98) works.
// R7: 16 cyc/MFMA structural. R8: NB=8 single block serial -> 86 us.
// R9: NB=4 + 2 blk/CU + lean k=64 MFMA -> 78 us. Model exact:
//     MFMA 816 cyc/SIMD/step (26.5%), VALU 711 (45.6%), ~30-50% idle =
//     serial M->bar->P->bar chain; cross-block slide imperfect.
// R10: ping-pong batch groups. NB=8 (A=0..3, B=4..7), 256 blocks x 256
//     thr, 1 blk/CU (waves_per_eu(1,1) caps 1 wave/SIMD -> even spread).
//     Each phase = M(group g) + P(group 1-g): independent -> compiler
//     interleaves MFMA+VALU in ONE wave stream (m98: 37%+43% co-issue).
//     [M_A(0)] bar; s-loop: [M_B(s)+P_A(s)] bar; [M_A(s+1)+P_B(s)] bar.
//     zbufA/zbufB separate statics for clean aliasing.
//
// MFMA tile: m=batch (4 of 16), n=hcol, K=64 (pure h@U). Per wave:
// t0-2 gate=wave cols 0/16/32; t3: wave3=fre, else gate=wave col48;
// t4 (wave0): gate3 col48. C layout: n=lane&15, m=reg (quad 0).

#define BB 2048
#define TT 60
#define DD 6
#define HH 64
#define FF 10
#define NB 8      // batches per block: group A = 0..3, group B = 4..7

#define HS 72     // h split per-batch stride in shorts
#define XCS 964   // xc per-batch stride in floats (60*16 + 4 pad)

typedef short bf16x8 __attribute__((ext_vector_type(8)));
typedef float f32x4  __attribute__((ext_vector_type(4)));

__device__ __forceinline__ unsigned short f2bf(float f) {
    union { float f; unsigned u; } v; v.f = f;
    unsigned r = v.u + 0x7fffu + ((v.u >> 16) & 1u);   // RNE
    return (unsigned short)(r >> 16);
}
__device__ __forceinline__ float bf2f(unsigned short b) {
    union { unsigned u; float f; } v; v.u = ((unsigned)b) << 16; return v.f;
}
__device__ __forceinline__ float hsig_f(float v) {
    return __builtin_amdgcn_fmed3f(fmaf(v, 0.16666666666666666f, 0.5f), 0.0f, 1.0f);
}
__device__ __forceinline__ float tanh_f(float x) {
    float xc = fminf(fmaxf(x, -12.0f), 12.0f);
    float e  = __builtin_amdgcn_exp2f(xc * 2.8853900817779268f); // 2*log2(e)
    return (e - 1.0f) * __builtin_amdgcn_rcpf(e + 1.0f);
}
__device__ __forceinline__ float uni(float v) {
    return __int_as_float(__builtin_amdgcn_readfirstlane(__float_as_int(v)));
}
__device__ __forceinline__ void pinv(bf16x8& v) { asm volatile("" : "+v"(v)); }

__global__ __launch_bounds__(256)
__attribute__((amdgpu_waves_per_eu(1, 1)))
void sfm_kernel(
    const float* __restrict__ x,
    const float* __restrict__ W_i,  const float* __restrict__ U_i,  const float* __restrict__ b_i,
    const float* __restrict__ W_ste,const float* __restrict__ U_ste,const float* __restrict__ b_ste,
    const float* __restrict__ W_fre,const float* __restrict__ U_fre,const float* __restrict__ b_fre,
    const float* __restrict__ W_c,  const float* __restrict__ U_c,  const float* __restrict__ b_c,
    const float* __restrict__ W_o,  const float* __restrict__ U_o,  const float* __restrict__ b_o,
    const float* __restrict__ U_a,  const float* __restrict__ b_a,
    const float* __restrict__ W_p,  const float* __restrict__ b_p,
    float* __restrict__ out)
{
    const int tid  = threadIdx.x;
    const int lane = tid & 63;
    const int wave = tid >> 6;      // 0..3
    const int q    = lane >> 4;     // quad 0..3
    const int n16  = lane & 15;
    const int b0   = blockIdx.x * NB;

    __shared__ __align__(16) float xc[NB * XCS];           // [b][s][0..5]=x, [6..15]=xf
    __shared__ __align__(16) unsigned short hhi[NB * HS];
    __shared__ __align__(16) unsigned short hlo[NB * HS];
    __shared__ __align__(16) float zbA[4 * 64 * 4];        // z group A
    __shared__ __align__(16) float zbB[4 * 64 * 4];        // z group B
    __shared__ __align__(16) float fbA[4 * 12];
    __shared__ __align__(16) float fbB[4 * 12];
    __shared__ __align__(16) float ctab[10 * 10 * 2];
    __shared__ float cstabB[10 * 2];
    __shared__ float red[4][NB];

    // ---- init 1: stage x fp32 (coalesced), base trig, zero h ----
    for (int i = tid; i < NB * TT * DD; i += 256) {
        const int b = i / (TT * DD), rem = i - b * (TT * DD);
        const int s = rem / DD, d = rem - s * DD;
        xc[b * XCS + s * 16 + d] = x[(size_t)b0 * (TT * DD) + i];
    }
    if (tid < 10) {
        const float CTc[10] = { 1.0f,  0.8090169943749475f,  0.30901699437494745f,
                               -0.30901699437494745f, -0.8090169943749475f, -1.0f,
                               -0.8090169943749475f, -0.30901699437494745f,
                                0.30901699437494745f,  0.8090169943749475f };
        const float STc[10] = { 0.0f,  0.5877852522924731f,  0.9510565162951535f,
                                0.9510565162951535f,  0.5877852522924731f,  0.0f,
                               -0.5877852522924731f, -0.9510565162951535f,
                               -0.9510565162951535f, -0.5877852522924731f };
        float cc = 0.0f, ss = 0.0f;
        #pragma unroll
        for (int j = 0; j < 10; ++j) if (tid == j) { cc = CTc[j]; ss = STc[j]; }
        cstabB[tid * 2] = cc; cstabB[tid * 2 + 1] = ss;
    }
    for (int i = tid; i < NB * HS; i += 256) { hhi[i] = 0; hlo[i] = 0; }
    __syncthreads();

    // ---- init 2: xf[b][s][f] = b_fre + x@W_fre; full ctab ----
    for (int item = tid; item < NB * TT; item += 256) {
        const int b = item / TT, s = item - b * TT;
        float xr[DD];
        #pragma unroll
        for (int d = 0; d < DD; ++d) xr[d] = xc[b * XCS + s * 16 + d];
        #pragma unroll
        for (int f = 0; f < FF; ++f) {
            float v = b_fre[f];
            #pragma unroll
            for (int d = 0; d < DD; ++d) v = fmaf(xr[d], W_fre[d * FF + f], v);
            xc[b * XCS + s * 16 + 6 + f] = v;
        }
    }
    if (tid < 100) {
        const int mm = tid / 10, ff = tid - mm * 10;
        const int idx = (ff * mm) % 10;
        ctab[tid * 2]     = cstabB[idx * 2];
        ctab[tid * 2 + 1] = cstabB[idx * 2 + 1];
    }

    // ---- B-frags (17 tiles, k=64) ----
    const int NT = (wave == 0) ? 5 : 4;
    bf16x8 Bh[5][2], Bl[5][2];
    #pragma unroll
    for (int t = 0; t < 5; ++t) {
        if (t >= NT) continue;
        const bool isfre = (t == 3 && wave == 3);
        const int g  = (t == 4) ? 3 : wave;
        const int cb = (t == 3 || t == 4) ? 48 : t * 16;
        const float* Up = isfre ? U_fre :
                          (g == 0) ? U_i : (g == 1) ? U_ste : (g == 2) ? U_c : U_o;
        #pragma unroll
        for (int c = 0; c < 2; ++c) {
            #pragma unroll
            for (int j = 0; j < 8; ++j) {
                const int kv = c * 32 + q * 8 + j;
                float v;
                if (isfre) v = (n16 < FF) ? Up[kv * FF + n16] : 0.0f;
                else       v = Up[kv * HH + cb + n16];
                const unsigned short hb = f2bf(v);
                Bh[t][c][j] = (short)hb;
                Bl[t][c][j] = (short)f2bf(v - bf2f(hb));
            }
            pinv(Bh[t][c]); pinv(Bl[t][c]);
        }
    }

    // ---- pointwise consts: pb = tid&3, pc = tid>>2 ----
    const int pb = tid & 3;
    const int pc = tid >> 2;
    const float bav = b_a[pc];
    const float wpv = W_p[pc];
    const float bpv = uni(b_p[0]);
    float uav[FF];
    #pragma unroll
    for (int f = 0; f < FF; ++f) uav[f] = uni(U_a[f]);
    float wxi[DD], wxs[DD], wxc[DD], wxo[DD];
    #pragma unroll
    for (int d = 0; d < DD; ++d) {
        wxi[d] = W_i[d * HH + pc];  wxs[d] = W_ste[d * HH + pc];
        wxc[d] = W_c[d * HH + pc];  wxo[d] = W_o[d * HH + pc];
    }
    const float bi = b_i[pc], bs = b_ste[pc], bc = b_c[pc], bo = b_o[pc];

    float Sre[2][FF], Sim[2][FF], hv[2];
    #pragma unroll
    for (int f = 0; f < FF; ++f) {
        Sre[0][f] = 0.0f; Sim[0][f] = 0.0f;
        Sre[1][f] = 0.0f; Sim[1][f] = 0.0f;
    }
    hv[0] = 0.0f; hv[1] = 0.0f;

    // ---- M: MFMA for group g at step s -> zb/fb ----
    auto do_M = [&](const int g, const int s, float* zb, float* fb) {
        const int ab = g * 4 + (n16 & 3);
        const unsigned short* hhp = &hhi[ab * HS];
        const unsigned short* hlp = &hlo[ab * HS];
        bf16x8 Ah[2], Al[2];
        #pragma unroll
        for (int c = 0; c < 2; ++c) {
            Ah[c] = *(const bf16x8*)&hhp[c * 32 + q * 8];
            Al[c] = *(const bf16x8*)&hlp[c * 32 + q * 8];
        }
        f32x4 acc[5];
        #pragma unroll
        for (int t = 0; t < 5; ++t) {
            if (t >= NT) continue;
            f32x4 a = {0.0f, 0.0f, 0.0f, 0.0f};
            #pragma unroll
            for (int c = 0; c < 2; ++c) {
                a = __builtin_amdgcn_mfma_f32_16x16x32_bf16(Al[c], Bh[t][c], a, 0, 0, 0);
                a = __builtin_amdgcn_mfma_f32_16x16x32_bf16(Ah[c], Bl[t][c], a, 0, 0, 0);
                a = __builtin_amdgcn_mfma_f32_16x16x32_bf16(Ah[c], Bh[t][c], a, 0, 0, 0);
            }
            acc[t] = a;
        }
        if (q == 0) {
            *(f32x4*)&zb[(wave * 64 +  0 + n16) * 4] = acc[0];
            *(f32x4*)&zb[(wave * 64 + 16 + n16) * 4] = acc[1];
            *(f32x4*)&zb[(wave * 64 + 32 + n16) * 4] = acc[2];
            if (wave == 3) {
                if (n16 < FF) {
                    #pragma unroll
                    for (int r = 0; r < 4; ++r)
                        fb[r * 12 + n16] = acc[3][r] + xc[(g * 4 + r) * XCS + s * 16 + 6 + n16];
                }
            } else {
                *(f32x4*)&zb[(wave * 64 + 48 + n16) * 4] = acc[3];
            }
            if (wave == 0)
                *(f32x4*)&zb[(3 * 64 + 48 + n16) * 4] = acc[4];
        }
    };

    // ---- P: pointwise for group g at step s ----
    auto do_P = [&](const int g, const int s, const float* zb, const float* fb,
                    const float* tp) {
        const int pbg = g * 4 + pb;
        const float4 xv4 = *(const float4*)&xc[pbg * XCS + s * 16];
        const float2 xv2 = *(const float2*)&xc[pbg * XCS + s * 16 + 4];
        const float xa[DD] = {xv4.x, xv4.y, xv4.z, xv4.w, xv2.x, xv2.y};

        float vi = bi, vs = bs, vc = bc, vo = bo;
        #pragma unroll
        for (int d = 0; d < DD; ++d) {
            vi = fmaf(xa[d], wxi[d], vi);
            vs = fmaf(xa[d], wxs[d], vs);
            vc = fmaf(xa[d], wxc[d], vc);
            vo = fmaf(xa[d], wxo[d], vo);
        }
        const float zi = zb[(0 * 64 + pc) * 4 + pb] + vi;
        const float zs = zb[(1 * 64 + pc) * 4 + pb] + vs;
        const float zc = zb[(2 * 64 + pc) * 4 + pb] + vc;
        const float zo = zb[(3 * 64 + pc) * 4 + pb] + vo;

        const f32x4 fb0 = *(const f32x4*)&fb[pb * 12];
        const f32x4 fb1 = *(const f32x4*)&fb[pb * 12 + 4];
        const f32x4 fb2 = *(const f32x4*)&fb[pb * 12 + 8];
        float fr[FF];
        #pragma unroll
        for (int f = 0; f < 4; ++f) fr[f] = hsig_f(fb0[f]);
        #pragma unroll
        for (int f = 0; f < 4; ++f) fr[4 + f] = hsig_f(fb1[f]);
        fr[8] = hsig_f(fb2[0]); fr[9] = hsig_f(fb2[1]);

        const float iv  = hsig_f(zi);
        const float stv = hsig_f(zs);
        const float ov  = hsig_f(zo);
        const float cv  = iv * tanh_f(zc);

        float aacc = bav;
        #pragma unroll
        for (int f = 0; f < FF; ++f) {
            const float2 tv = *(const float2*)&tp[f * 2];
            const float fc = stv * fr[f];
            Sre[g][f] = fmaf(fc, Sre[g][f], cv * tv.x);
            Sim[g][f] = fmaf(fc, Sim[g][f], cv * tv.y);
            const float A = fmaf(Sim[g][f], Sim[g][f], Sre[g][f] * Sre[g][f]);
            aacc = fmaf(A, uav[f], aacc);
        }
        hv[g] = ov * tanh_f(aacc);

        const unsigned short hb = f2bf(hv[g]);
        hhi[pbg * HS + pc] = hb;
        hlo[pbg * HS + pc] = f2bf(hv[g] - bf2f(hb));
    };

    __syncthreads();

    // ---- prologue: M_A(0) ----
    do_M(0, 0, zbA, fbA);
    __syncthreads();

    int m = 1;  // (s+1) % 10
    for (int s = 0; s < TT; ++s) {
        const float* tp = &ctab[m * 20];
        // phase 1: M_B(s) + P_A(s) — independent, interleavable
        do_M(1, s, zbB, fbB);
        do_P(0, s, zbA, fbA, tp);
        __syncthreads();
        // phase 2: M_A(s+1) + P_B(s)
        if (s + 1 < TT) do_M(0, s + 1, zbA, fbA);
        do_P(1, s, zbB, fbB, tp);
        __syncthreads();
        if (++m == 10) m = 0;
    }

    // ---- output: out[b] = sum_col h*W_p + b_p ----
    float v0 = hv[0] * wpv;
    v0 += __shfl_xor(v0, 4, 64);
    v0 += __shfl_xor(v0, 8, 64);
    v0 += __shfl_xor(v0, 16, 64);
    v0 += __shfl_xor(v0, 32, 64);
    float v1 = hv[1] * wpv;
    v1 += __shfl_xor(v1, 4, 64);
    v1 += __shfl_xor(v1, 8, 64);
    v1 += __shfl_xor(v1, 16, 64);
    v1 += __shfl_xor(v1, 32, 64);
    if (lane < 4) { red[wave][lane] = v0; red[wave][4 + lane] = v1; }
    __syncthreads();
    if (tid < NB)
        out[b0 + tid] = red[0][tid] + red[1][tid] + red[2][tid] + red[3][tid] + bpv;
}

extern "C" void kernel_launch(void* const* d_in, const int* in_sizes, int n_in,
                              void* d_out, int out_size, void* d_ws, size_t ws_size,
                              hipStream_t stream) {
    (void)in_sizes; (void)n_in; (void)d_ws; (void)ws_size; (void)out_size;
    const float* x     = (const float*)d_in[0];
    const float* W_i   = (const float*)d_in[1];
    const float* U_i   = (const float*)d_in[2];
    const float* b_i   = (const float*)d_in[3];
    const float* W_ste = (const float*)d_in[4];
    const float* U_ste = (const float*)d_in[5];
    const float* b_ste = (const float*)d_in[6];
    const float* W_fre = (const float*)d_in[7];
    const float* U_fre = (const float*)d_in[8];
    const float* b_fre = (const float*)d_in[9];
    const float* W_c   = (const float*)d_in[10];
    const float* U_c   = (const float*)d_in[11];
    const float* b_c   = (const float*)d_in[12];
    const float* W_o   = (const float*)d_in[13];
    const float* U_o   = (const float*)d_in[14];
    const float* b_o   = (const float*)d_in[15];
    const float* U_a   = (const float*)d_in[16];
    const float* b_a   = (const float*)d_in[17];
    const float* W_p   = (const float*)d_in[18];
    const float* b_p   = (const float*)d_in[19];

    sfm_kernel<<<BB / NB, 256, 0, stream>>>(
        x, W_i, U_i, b_i, W_ste, U_ste, b_ste, W_fre, U_fre, b_fre,
        W_c, U_c, b_c, W_o, U_o, b_o, U_a, b_a, W_p, b_p, (float*)d_out);
}

// Round 11
// 163.352 us; speedup vs baseline: 1.1701x; 1.1701x over previous
//
#include <hip/hip_runtime.h>

// SFM recurrent model via MFMA: B=2048, T=60, D=6, H=64, F=10, O=1.
//
// R1-R3: VALU readlane-GEMV, 183 us. R4: MFMA split-bf16 -> 100 us.
// R5: pre-split bf16 in LDS -> 83 us. R7: 16 cyc/MFMA structural.
// R9: NB=4 + 2 blk/CU + lean k=64 MFMA -> 78 us (best). Model exact:
//     MFMA 816 cyc/SIMD/step, VALU 711, ~28% idle.
// R10: static M+P interleave @1 wave/SIMD -> 110 us REGRESSION.
//     Lesson: HW 2-wave interleave (independent barrier domains) beats
//     static single-wave scheduling; stalls need a second wave.
// R11: R9 + term-stacking into unused m-rows: A' rows 0..3 = Ah(b0..3),
//     rows 4..7 = Al(b0..3) (8..15 zero). Per chunk: 2 chained MFMAs
//     (B=Bh then B=Bl); quad0 = Ah(Bh+Bl), quad1 = Al(Bh+Bl); P sums
//     main+lo (includes formerly-dropped AlBl). 102 -> 68 MFMA/block,
//     A-reads halved. fre tile folds lo via shfl_xor(16) on wave 3.
//
// MFMA tile: n=hcol, K=64 (pure h@U). Per wave: t0-2 gate=wave cols
// 0/16/32; t3: wave3=fre else gate=wave col48; t4 (wave0): gate3 col48.
// C layout: col=lane&15, row=(lane>>4)*4+reg -> quad0 rows 0..3 (main),
// quad1 rows 4..7 (lo). A layout: m=lane&15, k=(lane>>4)*8+j.

#define BB 2048
#define TT 60
#define DD 6
#define HH 64
#define FF 10
#define NB 4      // batches per block

#define HS 72     // h per-row stride in shorts (16 rows: 0-3 hi, 4-7 lo, 8-15 zero)
#define XCS 964   // xc per-batch stride in floats (60*16 + 4 pad)
#define ZOFF 1024 // zb2: lo-part offset (4*64*4 floats)

typedef short bf16x8 __attribute__((ext_vector_type(8)));
typedef float f32x4  __attribute__((ext_vector_type(4)));

__device__ __forceinline__ unsigned short f2bf(float f) {
    union { float f; unsigned u; } v; v.f = f;
    unsigned r = v.u + 0x7fffu + ((v.u >> 16) & 1u);   // RNE
    return (unsigned short)(r >> 16);
}
__device__ __forceinline__ float bf2f(unsigned short b) {
    union { unsigned u; float f; } v; v.u = ((unsigned)b) << 16; return v.f;
}
__device__ __forceinline__ float hsig_f(float v) {
    return __builtin_amdgcn_fmed3f(fmaf(v, 0.16666666666666666f, 0.5f), 0.0f, 1.0f);
}
__device__ __forceinline__ float tanh_f(float x) {
    float xc = fminf(fmaxf(x, -12.0f), 12.0f);
    float e  = __builtin_amdgcn_exp2f(xc * 2.8853900817779268f); // 2*log2(e)
    return (e - 1.0f) * __builtin_amdgcn_rcpf(e + 1.0f);
}
__device__ __forceinline__ float uni(float v) {
    return __int_as_float(__builtin_amdgcn_readfirstlane(__float_as_int(v)));
}
__device__ __forceinline__ void pinv(bf16x8& v) { asm volatile("" : "+v"(v)); }

__global__ __launch_bounds__(256, 2)
void sfm_kernel(
    const float* __restrict__ x,
    const float* __restrict__ W_i,  const float* __restrict__ U_i,  const float* __restrict__ b_i,
    const float* __restrict__ W_ste,const float* __restrict__ U_ste,const float* __restrict__ b_ste,
    const float* __restrict__ W_fre,const float* __restrict__ U_fre,const float* __restrict__ b_fre,
    const float* __restrict__ W_c,  const float* __restrict__ U_c,  const float* __restrict__ b_c,
    const float* __restrict__ W_o,  const float* __restrict__ U_o,  const float* __restrict__ b_o,
    const float* __restrict__ U_a,  const float* __restrict__ b_a,
    const float* __restrict__ W_p,  const float* __restrict__ b_p,
    float* __restrict__ out)
{
    const int tid  = threadIdx.x;
    const int lane = tid & 63;
    const int wave = tid >> 6;      // 0..3
    const int q    = lane >> 4;     // quad 0..3
    const int n16  = lane & 15;
    const int b0   = blockIdx.x * NB;

    __shared__ __align__(16) float xc[NB * XCS];            // [b][s][0..5]=x, [6..15]=xf
    __shared__ __align__(16) unsigned short hsp[16 * HS];   // rows 0-3 hi(b), 4-7 lo(b), 8-15 zero
    __shared__ __align__(16) float zb2[2 * 4 * 64 * 4];     // [part][g][col][b]
    __shared__ __align__(16) float fb[NB * 12];             // zfre[b][f], main+lo folded, +xf
    __shared__ __align__(16) float ctab[10 * 10 * 2];
    __shared__ float cstabB[10 * 2];
    __shared__ float red[4][NB];

    // ---- init 1: stage x fp32 (coalesced), base trig, zero h rows ----
    for (int i = tid; i < NB * TT * DD; i += 256) {
        const int b = i / (TT * DD), rem = i - b * (TT * DD);
        const int s = rem / DD, d = rem - s * DD;
        xc[b * XCS + s * 16 + d] = x[(size_t)b0 * (TT * DD) + i];
    }
    if (tid < 10) {
        const float CTc[10] = { 1.0f,  0.8090169943749475f,  0.30901699437494745f,
                               -0.30901699437494745f, -0.8090169943749475f, -1.0f,
                               -0.8090169943749475f, -0.30901699437494745f,
                                0.30901699437494745f,  0.8090169943749475f };
        const float STc[10] = { 0.0f,  0.5877852522924731f,  0.9510565162951535f,
                                0.9510565162951535f,  0.5877852522924731f,  0.0f,
                               -0.5877852522924731f, -0.9510565162951535f,
                               -0.9510565162951535f, -0.5877852522924731f };
        float cc = 0.0f, ss = 0.0f;
        #pragma unroll
        for (int j = 0; j < 10; ++j) if (tid == j) { cc = CTc[j]; ss = STc[j]; }
        cstabB[tid * 2] = cc; cstabB[tid * 2 + 1] = ss;
    }
    for (int i = tid; i < 16 * HS; i += 256) hsp[i] = 0;   // rows 8..15 stay zero forever
    __syncthreads();

    // ---- init 2: xf[b][s][f] = b_fre + x@W_fre; full ctab ----
    if (tid < NB * TT) {
        const int b = tid / TT, s = tid - b * TT;
        float xr[DD];
        #pragma unroll
        for (int d = 0; d < DD; ++d) xr[d] = xc[b * XCS + s * 16 + d];
        #pragma unroll
        for (int f = 0; f < FF; ++f) {
            float v = b_fre[f];
            #pragma unroll
            for (int d = 0; d < DD; ++d) v = fmaf(xr[d], W_fre[d * FF + f], v);
            xc[b * XCS + s * 16 + 6 + f] = v;
        }
    }
    if (tid < 100) {
        const int mm = tid / 10, ff = tid - mm * 10;
        const int idx = (ff * mm) % 10;
        ctab[tid * 2]     = cstabB[idx * 2];
        ctab[tid * 2 + 1] = cstabB[idx * 2 + 1];
    }

    // ---- B-frags (17 tiles, k=64) ----
    const int NT = (wave == 0) ? 5 : 4;
    bf16x8 Bh[5][2], Bl[5][2];
    #pragma unroll
    for (int t = 0; t < 5; ++t) {
        if (t >= NT) continue;
        const bool isfre = (t == 3 && wave == 3);
        const int g  = (t == 4) ? 3 : wave;
        const int cb = (t == 3 || t == 4) ? 48 : t * 16;
        const float* Up = isfre ? U_fre :
                          (g == 0) ? U_i : (g == 1) ? U_ste : (g == 2) ? U_c : U_o;
        #pragma unroll
        for (int c = 0; c < 2; ++c) {
            #pragma unroll
            for (int j = 0; j < 8; ++j) {
                const int kv = c * 32 + q * 8 + j;
                float v;
                if (isfre) v = (n16 < FF) ? Up[kv * FF + n16] : 0.0f;
                else       v = Up[kv * HH + cb + n16];
                const unsigned short hb = f2bf(v);
                Bh[t][c][j] = (short)hb;
                Bl[t][c][j] = (short)f2bf(v - bf2f(hb));
            }
            pinv(Bh[t][c]); pinv(Bl[t][c]);
        }
    }

    // ---- pointwise consts: pb = tid&3, pc = tid>>2 ----
    const int pb = tid & (NB - 1);
    const int pc = tid >> 2;
    const float bav = b_a[pc];
    const float wpv = W_p[pc];
    const float bpv = uni(b_p[0]);
    float uav[FF];
    #pragma unroll
    for (int f = 0; f < FF; ++f) uav[f] = uni(U_a[f]);
    float wxi[DD], wxs[DD], wxc[DD], wxo[DD];
    #pragma unroll
    for (int d = 0; d < DD; ++d) {
        wxi[d] = W_i[d * HH + pc];  wxs[d] = W_ste[d * HH + pc];
        wxc[d] = W_c[d * HH + pc];  wxo[d] = W_o[d * HH + pc];
    }
    const float bi = b_i[pc], bs = b_ste[pc], bc = b_c[pc], bo = b_o[pc];

    float Sre[FF], Sim[FF];
    #pragma unroll
    for (int f = 0; f < FF; ++f) { Sre[f] = 0.0f; Sim[f] = 0.0f; }
    float hv = 0.0f;

    // A-frag source: row = n16 (0..3 hi(b), 4..7 lo(b), 8..15 zero)
    const unsigned short* hrp = &hsp[n16 * HS];

    __syncthreads();

    int m = 1;  // (s+1) % 10
    for (int s = 0; s < TT; ++s) {
        // ---- A'-frags: ONE b128 per chunk (rows pre-structured in LDS) ----
        bf16x8 A0 = *(const bf16x8*)&hrp[0 * 32 + q * 8];
        bf16x8 A1 = *(const bf16x8*)&hrp[1 * 32 + q * 8];

        // ---- MFMAs: per tile 4 chained (A',Bh0)(A',Bl0)(A',Bh1)(A',Bl1) ----
        f32x4 acc[5];
        #pragma unroll
        for (int t = 0; t < 5; ++t) {
            if (t >= NT) continue;
            f32x4 a = {0.0f, 0.0f, 0.0f, 0.0f};
            a = __builtin_amdgcn_mfma_f32_16x16x32_bf16(A0, Bh[t][0], a, 0, 0, 0);
            a = __builtin_amdgcn_mfma_f32_16x16x32_bf16(A0, Bl[t][0], a, 0, 0, 0);
            a = __builtin_amdgcn_mfma_f32_16x16x32_bf16(A1, Bh[t][1], a, 0, 0, 0);
            a = __builtin_amdgcn_mfma_f32_16x16x32_bf16(A1, Bl[t][1], a, 0, 0, 0);
            acc[t] = a;
        }

        // ---- write z: quad0 -> main, quad1 -> lo (R9 conflict-free pattern x2) ----
        if (q < 2) {
            float* zq = &zb2[q * ZOFF];
            *(f32x4*)&zq[(wave * 64 +  0 + n16) * 4] = acc[0];
            *(f32x4*)&zq[(wave * 64 + 16 + n16) * 4] = acc[1];
            *(f32x4*)&zq[(wave * 64 + 32 + n16) * 4] = acc[2];
            if (wave != 3)
                *(f32x4*)&zq[(wave * 64 + 48 + n16) * 4] = acc[3];
            if (wave == 0)
                *(f32x4*)&zq[(3 * 64 + 48 + n16) * 4] = acc[4];
        }
        if (wave == 3) {   // fre tile: fold lo into main via shfl, add xf, write
            f32x4 af = acc[3];
            #pragma unroll
            for (int r = 0; r < 4; ++r) af[r] += __shfl_xor(acc[3][r], 16, 64);
            if (q == 0 && n16 < FF) {
                #pragma unroll
                for (int r = 0; r < 4; ++r)
                    fb[r * 12 + n16] = af[r] + xc[r * XCS + s * 16 + 6 + n16];
            }
        }
        __syncthreads();

        // ---- pointwise: batch pb, col pc ----
        const float4 xv4 = *(const float4*)&xc[pb * XCS + s * 16];
        const float2 xv2 = *(const float2*)&xc[pb * XCS + s * 16 + 4];
        const float xa[DD] = {xv4.x, xv4.y, xv4.z, xv4.w, xv2.x, xv2.y};

        float vi = bi, vs = bs, vc = bc, vo = bo;
        #pragma unroll
        for (int d = 0; d < DD; ++d) {
            vi = fmaf(xa[d], wxi[d], vi);
            vs = fmaf(xa[d], wxs[d], vs);
            vc = fmaf(xa[d], wxc[d], vc);
            vo = fmaf(xa[d], wxo[d], vo);
        }
        const int zo4 = pc * 4 + pb;
        const float zi = zb2[(0 * 64) * 4 + zo4] + zb2[ZOFF + (0 * 64) * 4 + zo4] + vi;
        const float zs = zb2[(1 * 64) * 4 + zo4] + zb2[ZOFF + (1 * 64) * 4 + zo4] + vs;
        const float zc = zb2[(2 * 64) * 4 + zo4] + zb2[ZOFF + (2 * 64) * 4 + zo4] + vc;
        const float zo = zb2[(3 * 64) * 4 + zo4] + zb2[ZOFF + (3 * 64) * 4 + zo4] + vo;

        const f32x4 fb0 = *(const f32x4*)&fb[pb * 12];
        const f32x4 fb1 = *(const f32x4*)&fb[pb * 12 + 4];
        const f32x4 fb2 = *(const f32x4*)&fb[pb * 12 + 8];
        float fr[FF];
        #pragma unroll
        for (int f = 0; f < 4; ++f) fr[f] = hsig_f(fb0[f]);
        #pragma unroll
        for (int f = 0; f < 4; ++f) fr[4 + f] = hsig_f(fb1[f]);
        fr[8] = hsig_f(fb2[0]); fr[9] = hsig_f(fb2[1]);

        const float iv  = hsig_f(zi);
        const float stv = hsig_f(zs);
        const float ov  = hsig_f(zo);
        const float cv  = iv * tanh_f(zc);

        const float* tp = &ctab[m * 20];
        float aacc0 = bav, aacc1 = 0.0f;   // split 10-deep chain in two
        #pragma unroll
        for (int f = 0; f < FF; ++f) {
            const float2 tv = *(const float2*)&tp[f * 2];
            const float fc = stv * fr[f];
            Sre[f] = fmaf(fc, Sre[f], cv * tv.x);
            Sim[f] = fmaf(fc, Sim[f], cv * tv.y);
            const float A = fmaf(Sim[f], Sim[f], Sre[f] * Sre[f]);
            if (f & 1) aacc1 = fmaf(A, uav[f], aacc1);
            else       aacc0 = fmaf(A, uav[f], aacc0);
        }
        hv = ov * tanh_f(aacc0 + aacc1);

        // split h -> bf16 hi/lo into structured rows (ONLY conversion point)
        {
            const unsigned short hb = f2bf(hv);
            hsp[pb * HS + pc]       = hb;
            hsp[(4 + pb) * HS + pc] = f2bf(hv - bf2f(hb));
        }
        if (++m == 10) m = 0;
        __syncthreads();
    }

    // ---- output: out[b] = sum_col h*W_p + b_p ----
    float val = hv * wpv;
    val += __shfl_xor(val, 4, 64);
    val += __shfl_xor(val, 8, 64);
    val += __shfl_xor(val, 16, 64);
    val += __shfl_xor(val, 32, 64);
    if (lane < NB) red[wave][lane] = val;
    __syncthreads();
    if (tid < NB)
        out[b0 + tid] = red[0][tid] + red[1][tid] + red[2][tid] + red[3][tid] + bpv;
}

extern "C" void kernel_launch(void* const* d_in, const int* in_sizes, int n_in,
                              void* d_out, int out_size, void* d_ws, size_t ws_size,
                              hipStream_t stream) {
    (void)in_sizes; (void)n_in; (void)d_ws; (void)ws_size; (void)out_size;
    const float* x     = (const float*)d_in[0];
    const float* W_i   = (const float*)d_in[1];
    const float* U_i   = (const float*)d_in[2];
    const float* b_i   = (const float*)d_in[3];
    const float* W_ste = (const float*)d_in[4];
    const float* U_ste = (const float*)d_in[5];
    const float* b_ste = (const float*)d_in[6];
    const float* W_fre = (const float*)d_in[7];
    const float* U_fre = (const float*)d_in[8];
    const float* b_fre = (const float*)d_in[9];
    const float* W_c   = (const float*)d_in[10];
    const float* U_c   = (const float*)d_in[11];
    const float* b_c   = (const float*)d_in[12];
    const float* W_o   = (const float*)d_in[13];
    const float* U_o   = (const float*)d_in[14];
    const float* b_o   = (const float*)d_in[15];
    const float* U_a   = (const float*)d_in[16];
    const float* b_a   = (const float*)d_in[17];
    const float* W_p   = (const float*)d_in[18];
    const float* b_p   = (const float*)d_in[19];

    sfm_kernel<<<BB / NB, 256, 0, stream>>>(
        x, W_i, U_i, b_i, W_ste, U_ste, b_ste, W_fre, U_fre, b_fre,
        W_c, U_c, b_c, W_o, U_o, b_o, U_a, b_a, W_p, b_p, (float*)d_out);
}

// Round 12
// 157.068 us; speedup vs baseline: 1.2169x; 1.0400x over previous
//
#include <hip/hip_runtime.h>

// SFM recurrent model via MFMA: B=2048, T=60, D=6, H=64, F=10, O=1.
//
// R1-R3: VALU readlane-GEMV, 183 us. R4: MFMA split-bf16 -> 100 us.
// R5-R11: 78-111 us band. Lessons: 16cyc/MFMA structural (R7); 2 blk/CU
//   slide real (R6/R9); 1-wave/SIMD static interleave fails (R10);
//   work-shaving inside M-phase doesn't cut wall (R11: busy -17%,
//   wall +7% -- step is serial-chain-bound).
// R12: TRANSPOSED GEMM. m = hcol (A = U^T STATIC, 16/16 rows used),
//   n-cols 0-7 = h_hi(b0..7), 8-15 = h_lo(b0..7) (16/16 cols used).
//   One B-frag/chunk; chain (Ah,B)(Al,B): col sums give FULL product
//   incl lo*lo. x@W + bias ride k=64..70 (presplit xsp record, R5);
//   fre tile absorbs W_fre/b_fre. 17 tiles x 6 = 102 MFMA/block for
//   NB=8 -> 2.4x batch-efficiency of R11. 256 blocks x 512 thr
//   (8 waves, 2/SIMD); P = 1 (b,col)/thread, ~140 VALU, no x@W.
//
// Layouts (guide-verified): A[m=lane&15][k=quad*8+j]; B[k=quad*8+j]
// [n=lane&15]; C col=lane&15 (n), row=quad*4+reg (m=hcol-in-tile).

#define BB 2048
#define TT 60
#define DD 6
#define HH 64
#define FF 10
#define NB 8      // batches per block

#define XS 968    // xsp per-batch stride in shorts (60*16 + 8 pad)
#define HSK 72    // hsp2 row stride in shorts (16 rows: 0-7 hi(b), 8-15 lo(b))
#define ZC 68     // zt hcol stride in floats (pad 64->68: banks spread)

typedef short bf16x8 __attribute__((ext_vector_type(8)));
typedef float f32x4  __attribute__((ext_vector_type(4)));

__device__ __forceinline__ unsigned short f2bf(float f) {
    union { float f; unsigned u; } v; v.f = f;
    unsigned r = v.u + 0x7fffu + ((v.u >> 16) & 1u);   // RNE
    return (unsigned short)(r >> 16);
}
__device__ __forceinline__ float bf2f(unsigned short b) {
    union { unsigned u; float f; } v; v.u = ((unsigned)b) << 16; return v.f;
}
__device__ __forceinline__ float hsig_f(float v) {
    return __builtin_amdgcn_fmed3f(fmaf(v, 0.16666666666666666f, 0.5f), 0.0f, 1.0f);
}
__device__ __forceinline__ float tanh_f(float x) {
    float xc = fminf(fmaxf(x, -12.0f), 12.0f);
    float e  = __builtin_amdgcn_exp2f(xc * 2.8853900817779268f); // 2*log2(e)
    return (e - 1.0f) * __builtin_amdgcn_rcpf(e + 1.0f);
}
__device__ __forceinline__ float uni(float v) {
    return __int_as_float(__builtin_amdgcn_readfirstlane(__float_as_int(v)));
}
__device__ __forceinline__ void pinv(bf16x8& v) { asm volatile("" : "+v"(v)); }

__global__ __launch_bounds__(512, 1)
void sfm_kernel(
    const float* __restrict__ x,
    const float* __restrict__ W_i,  const float* __restrict__ U_i,  const float* __restrict__ b_i,
    const float* __restrict__ W_ste,const float* __restrict__ U_ste,const float* __restrict__ b_ste,
    const float* __restrict__ W_fre,const float* __restrict__ U_fre,const float* __restrict__ b_fre,
    const float* __restrict__ W_c,  const float* __restrict__ U_c,  const float* __restrict__ b_c,
    const float* __restrict__ W_o,  const float* __restrict__ U_o,  const float* __restrict__ b_o,
    const float* __restrict__ U_a,  const float* __restrict__ b_a,
    const float* __restrict__ W_p,  const float* __restrict__ b_p,
    float* __restrict__ out)
{
    const int tid  = threadIdx.x;
    const int lane = tid & 63;
    const int wave = tid >> 6;      // 0..7
    const int q    = lane >> 4;     // quad 0..3
    const int n16  = lane & 15;
    const int b0   = blockIdx.x * NB;

    __shared__ __align__(16) unsigned short xsp[NB * XS];   // presplit x records
    __shared__ __align__(16) unsigned short hsp2[16 * HSK]; // rows 0-7 hhi(b), 8-15 hlo(b)
    __shared__ __align__(16) float zt[4 * 16 * ZC];         // [g][col(part,b)][hcol]
    __shared__ __align__(16) float fb[NB * 12];             // zfre[b][f], parts folded
    __shared__ __align__(16) float ctab[10 * 10 * 2];
    __shared__ float cstabB[10 * 2];
    __shared__ float red[8][8];

    // ---- init 1: stage + pre-split x (one (b,s) record per thread) ----
    if (tid < NB * TT) {
        const float* xg = x + (size_t)b0 * (TT * DD) + tid * DD;
        const int b = tid / TT, s = tid - b * TT;
        unsigned short* dst = &xsp[b * XS + s * 16];
        #pragma unroll
        for (int d = 0; d < DD; ++d) {
            const float v = xg[d];
            const unsigned short hb = f2bf(v);
            dst[d]     = hb;
            dst[8 + d] = f2bf(v - bf2f(hb));
        }
        dst[6] = 0x3F80; dst[7] = 0;   // k=70 bias row: 1.0 (hi), k=71: 0
        dst[14] = 0; dst[15] = 0;      // lo-part: k=70,71 = 0
    }
    if (tid < 10) {
        const float CTc[10] = { 1.0f,  0.8090169943749475f,  0.30901699437494745f,
                               -0.30901699437494745f, -0.8090169943749475f, -1.0f,
                               -0.8090169943749475f, -0.30901699437494745f,
                                0.30901699437494745f,  0.8090169943749475f };
        const float STc[10] = { 0.0f,  0.5877852522924731f,  0.9510565162951535f,
                                0.9510565162951535f,  0.5877852522924731f,  0.0f,
                               -0.5877852522924731f, -0.9510565162951535f,
                               -0.9510565162951535f, -0.5877852522924731f };
        float cc = 0.0f, ss = 0.0f;
        #pragma unroll
        for (int j = 0; j < 10; ++j) if (tid == j) { cc = CTc[j]; ss = STc[j]; }
        cstabB[tid * 2] = cc; cstabB[tid * 2 + 1] = ss;
    }
    for (int i = tid; i < 16 * HSK; i += 512) hsp2[i] = 0;   // h = 0 (hi & lo)
    __syncthreads();
    if (tid < 100) {
        const int mm = tid / 10, ff = tid - mm * 10;
        const int idx = (ff * mm) % 10;
        ctab[tid * 2]     = cstabB[idx * 2];
        ctab[tid * 2 + 1] = cstabB[idx * 2 + 1];
    }

    // ---- A-frags (STATIC, U^T orientation): wave w owns gate tiles
    //      gt=2w, 2w+1 (g=gt>>2, mt=gt&3); wave 7 adds fre tile (t=2).
    //      A[m=n16][k = c*32 + q*8 + j]; k: 0-63 U, 64-69 W, 70 bias. ----
    const int NTILE = (wave == 7) ? 3 : 2;
    bf16x8 Ah[3][3], Al[3][3];
    #pragma unroll
    for (int t = 0; t < 3; ++t) {
        if (t >= NTILE) continue;
        const bool isfre = (wave == 7 && t == 2);
        const int gt = 2 * wave + t;
        const int g  = gt >> 2, mt = gt & 3;
        const int col = mt * 16 + n16;
        const float* Ug = (g == 0) ? U_i : (g == 1) ? U_ste : (g == 2) ? U_c : U_o;
        const float* Wg = (g == 0) ? W_i : (g == 1) ? W_ste : (g == 2) ? W_c : W_o;
        const float* bg = (g == 0) ? b_i : (g == 1) ? b_ste : (g == 2) ? b_c : b_o;
        #pragma unroll
        for (int c = 0; c < 3; ++c) {
            #pragma unroll
            for (int j = 0; j < 8; ++j) {
                const int kv = c * 32 + q * 8 + j;
                float v = 0.0f;
                if (!isfre) {
                    if      (kv < 64)  v = Ug[kv * HH + col];
                    else if (kv < 70)  v = Wg[(kv - 64) * HH + col];
                    else if (kv == 70) v = bg[col];
                } else if (n16 < FF) {
                    if      (kv < 64)  v = U_fre[kv * FF + n16];
                    else if (kv < 70)  v = W_fre[(kv - 64) * FF + n16];
                    else if (kv == 70) v = b_fre[n16];
                }
                const unsigned short hb = f2bf(v);
                Ah[t][c][j] = (short)hb;
                Al[t][c][j] = (short)f2bf(v - bf2f(hb));
            }
            pinv(Ah[t][c]); pinv(Al[t][c]);
        }
    }

    // ---- pointwise consts: pb = tid&7, pc = tid>>3 (0..63) ----
    const int pb = tid & 7;
    const int pc = tid >> 3;
    const float bav = b_a[pc];
    const float wpv = W_p[pc];
    const float bpv = uni(b_p[0]);
    float uav[FF];
    #pragma unroll
    for (int f = 0; f < FF; ++f) uav[f] = uni(U_a[f]);

    float Sre[FF], Sim[FF];
    #pragma unroll
    for (int f = 0; f < FF; ++f) { Sre[f] = 0.0f; Sim[f] = 0.0f; }
    float hv = 0.0f;

    // B-frag addresses (dynamic h + x record)
    const unsigned short* hrp = &hsp2[n16 * HSK];
    const unsigned short* xrp = &xsp[(n16 & 7) * XS + (n16 >> 3) * 8];

    __syncthreads();

    int m = 1;  // (s+1) % 10
    for (int s = 0; s < TT; ++s) {
        // ---- B-frags: h chunks (all lanes), x chunk (q0 rows 64-71) ----
        const bf16x8 B0 = *(const bf16x8*)&hrp[q * 8];
        const bf16x8 B1 = *(const bf16x8*)&hrp[32 + q * 8];
        const bf16x8 xv = *(const bf16x8*)&xrp[s * 16];
        const bf16x8 zf = {0, 0, 0, 0, 0, 0, 0, 0};
        const bf16x8 B2 = (q == 0) ? xv : zf;

        // ---- MFMAs: per tile 6 chained (Ah,B)(Al,B) x 3 chunks ----
        f32x4 acc[3];
        #pragma unroll
        for (int t = 0; t < 3; ++t) {
            if (t >= NTILE) continue;
            f32x4 a = {0.0f, 0.0f, 0.0f, 0.0f};
            a = __builtin_amdgcn_mfma_f32_16x16x32_bf16(Ah[t][0], B0, a, 0, 0, 0);
            a = __builtin_amdgcn_mfma_f32_16x16x32_bf16(Al[t][0], B0, a, 0, 0, 0);
            a = __builtin_amdgcn_mfma_f32_16x16x32_bf16(Ah[t][1], B1, a, 0, 0, 0);
            a = __builtin_amdgcn_mfma_f32_16x16x32_bf16(Al[t][1], B1, a, 0, 0, 0);
            a = __builtin_amdgcn_mfma_f32_16x16x32_bf16(Ah[t][2], B2, a, 0, 0, 0);
            a = __builtin_amdgcn_mfma_f32_16x16x32_bf16(Al[t][2], B2, a, 0, 0, 0);
            acc[t] = a;
        }

        // ---- write z: lane (n16=col, q) holds hcols mt*16+q*4..+3 ----
        #pragma unroll
        for (int t = 0; t < 2; ++t) {
            const int gt = 2 * wave + t;
            const int g  = gt >> 2, mt = gt & 3;
            *(f32x4*)&zt[(g * 16 + n16) * ZC + mt * 16 + q * 4] = acc[t];
        }
        if (wave == 7) {   // fre: fold parts (col b + col b+8) via shfl, write fb[b][f]
            f32x4 af;
            #pragma unroll
            for (int r = 0; r < 4; ++r)
                af[r] = acc[2][r] + __shfl_xor(acc[2][r], 8, 64);
            if (n16 < 8) {
                #pragma unroll
                for (int r = 0; r < 4; ++r) {
                    const int f = q * 4 + r;
                    if (f < FF) fb[n16 * 12 + f] = af[r];
                }
            }
        }
        __syncthreads();

        // ---- P: batch pb, col pc; z = hi-col + lo-col (full product) ----
        const float zi = zt[(0 * 16 + pb) * ZC + pc] + zt[(0 * 16 + pb + 8) * ZC + pc];
        const float zs = zt[(1 * 16 + pb) * ZC + pc] + zt[(1 * 16 + pb + 8) * ZC + pc];
        const float zc = zt[(2 * 16 + pb) * ZC + pc] + zt[(2 * 16 + pb + 8) * ZC + pc];
        const float zo = zt[(3 * 16 + pb) * ZC + pc] + zt[(3 * 16 + pb + 8) * ZC + pc];

        float fr[FF];
        #pragma unroll
        for (int f = 0; f < FF; ++f) fr[f] = hsig_f(fb[pb * 12 + f]);

        const float iv  = hsig_f(zi);
        const float stv = hsig_f(zs);
        const float ov  = hsig_f(zo);
        const float cv  = iv * tanh_f(zc);

        const float* tp = &ctab[m * 20];
        float aacc0 = bav, aacc1 = 0.0f;
        #pragma unroll
        for (int f = 0; f < FF; ++f) {
            const float2 tv = *(const float2*)&tp[f * 2];
            const float fc = stv * fr[f];
            Sre[f] = fmaf(fc, Sre[f], cv * tv.x);
            Sim[f] = fmaf(fc, Sim[f], cv * tv.y);
            const float A = fmaf(Sim[f], Sim[f], Sre[f] * Sre[f]);
            if (f & 1) aacc1 = fmaf(A, uav[f], aacc1);
            else       aacc0 = fmaf(A, uav[f], aacc0);
        }
        hv = ov * tanh_f(aacc0 + aacc1);

        // split h -> bf16 hi/lo rows (the ONLY conversion point)
        {
            const unsigned short hb = f2bf(hv);
            hsp2[pb * HSK + pc]       = hb;
            hsp2[(8 + pb) * HSK + pc] = f2bf(hv - bf2f(hb));
        }
        if (++m == 10) m = 0;
        __syncthreads();
    }

    // ---- output: out[b] = sum_col h*W_p + b_p ----
    // lane bits: pb = lane&7, pc-octet bits = lane>>3 -> fold lanes 8,16,32
    float val = hv * wpv;
    val += __shfl_xor(val, 8, 64);
    val += __shfl_xor(val, 16, 64);
    val += __shfl_xor(val, 32, 64);
    if (lane < 8) red[wave][lane] = val;
    __syncthreads();
    if (tid < NB) {
        float acc = bpv;
        #pragma unroll
        for (int w = 0; w < 8; ++w) acc += red[w][tid];
        out[b0 + tid] = acc;
    }
}

extern "C" void kernel_launch(void* const* d_in, const int* in_sizes, int n_in,
                              void* d_out, int out_size, void* d_ws, size_t ws_size,
                              hipStream_t stream) {
    (void)in_sizes; (void)n_in; (void)d_ws; (void)ws_size; (void)out_size;
    const float* x     = (const float*)d_in[0];
    const float* W_i   = (const float*)d_in[1];
    const float* U_i   = (const float*)d_in[2];
    const float* b_i   = (const float*)d_in[3];
    const float* W_ste = (const float*)d_in[4];
    const float* U_ste = (const float*)d_in[5];
    const float* b_ste = (const float*)d_in[6];
    const float* W_fre = (const float*)d_in[7];
    const float* U_fre = (const float*)d_in[8];
    const float* b_fre = (const float*)d_in[9];
    const float* W_c   = (const float*)d_in[10];
    const float* U_c   = (const float*)d_in[11];
    const float* b_c   = (const float*)d_in[12];
    const float* W_o   = (const float*)d_in[13];
    const float* U_o   = (const float*)d_in[14];
    const float* b_o   = (const float*)d_in[15];
    const float* U_a   = (const float*)d_in[16];
    const float* b_a   = (const float*)d_in[17];
    const float* W_p   = (const float*)d_in[18];
    const float* b_p   = (const float*)d_in[19];

    sfm_kernel<<<BB / NB, 512, 0, stream>>>(
        x, W_i, U_i, b_i, W_ste, U_ste, b_ste, W_fre, U_fre, b_fre,
        W_c, U_c, b_c, W_o, U_o, b_o, U_a, b_a, W_p, b_p, (float*)d_out);
}